// Round 26
// baseline (114.455 us; speedup 1.0000x reference)
//
#include <hip/hip_runtime.h>
#include <math.h>

#define NB 8
#define NC 128
#define NP 96
#define ND 128
#define NH 8
#define NR 16

typedef __attribute__((ext_vector_type(8))) short short8;
typedef __attribute__((ext_vector_type(4))) short s16x4;
typedef __attribute__((ext_vector_type(4))) float f32x4;
typedef __attribute__((ext_vector_type(4))) unsigned u32x4;

#define MFMA(a, b, c) __builtin_amdgcn_mfma_f32_16x16x32_bf16((a), (b), (c), 0, 0, 0)

// K=16 bf16 MFMA for logits (exact K, all 64 lanes, A/B = 2 VGPRs)
#if __has_builtin(__builtin_amdgcn_mfma_f32_16x16x16_bf16)
#define MFMA16(a, b, c) __builtin_amdgcn_mfma_f32_16x16x16_bf16((a), (b), (c), 0, 0, 0)
#else
#define MFMA16(a, b, c) __builtin_amdgcn_mfma_f32_16x16x16bf16_1k((a), (b), (c), 0, 0, 0)
#endif

// log2(e) folded into the Qu projection scale so softmax uses exp2 directly
#define QU_SCALE (0.25f * 1.44269504f)

__device__ __forceinline__ short8 s8(u32x4 u) { return __builtin_bit_cast(short8, u); }

// fp32 -> bf16 via native cast (RNE; compiler emits cvt_pk for pairs)
__device__ __forceinline__ short bfh(float x) {
  __bf16 b = (__bf16)x;
  return __builtin_bit_cast(short, b);
}

// hi pack of 2 floats -> 2 bf16 in one u32
__device__ __forceinline__ unsigned hi2(float a, float b) {
  unsigned short ua = __builtin_bit_cast(unsigned short, (__bf16)a);
  unsigned short ub = __builtin_bit_cast(unsigned short, (__bf16)b);
  return (unsigned)ua | ((unsigned)ub << 16);
}

// fast exp2: raw v_exp_f32
__device__ __forceinline__ float fexp2(float x) {
#if __has_builtin(__builtin_amdgcn_exp2f)
  return __builtin_amdgcn_exp2f(x);
#else
  return exp2f(x);
#endif
}

// LDS row strides in shorts
#define TS_Z 136   // z-hi    [96][136]
#define TS_Q 76    // cmsg Q  [rows][76]   (38 words -> ~2-way on b64 reads)
#define TS_QA 268  // tmsg Q-all [96][268] (134 words -> same ~2-way pattern)
#define TS_T 104   // abar    [96][104]
#define TS_W 136   // W tile  [16][136] per nt

// ================= time-message body: idx -> (b, c) =================
// ALL-HEADS restructure: Q for all 4 head-pairs lives in one buffer
// qall[96][268] (col = hp*64 + nt*16 + lm). Proj sweeps all 4 hp with ZERO
// intervening barriers (disjoint writes, read-only zhi), then ONE barrier,
// then all logits (read-only qall). 3 barriers total (was 7).
__device__ __forceinline__ void tmsg_body(
    int idx, const float* __restrict__ qz, const float* __restrict__ wu,
    const float* __restrict__ wv, float* __restrict__ out, short* smem) {
  short* zhi  = smem;                   // [96][136] = 13056
  short* qall = smem + NP * TS_Z;       // [96][268] = 25728
  short* ahi  = smem;                   // [96][104] (phase2, over dead zhi)

  const int tid = threadIdx.x;
  const int l = tid & 63, w = tid >> 6;
  const int lm = l & 15, lk = l >> 4;
  const int c = idx & 127, b = idx >> 7;
  const float* zg = qz + ((size_t)(b * NC + c) * NP) * ND;

  // ---- stage z -> bf16 hi only ----
  for (int i = tid; i < NP * 32; i += 512) {
    int p = i >> 5, s = i & 31;
    float4 v = ((const float4*)zg)[i];
    *(uint2*)&zhi[p * TS_Z + 4 * s] = make_uint2(hi2(v.x, v.y), hi2(v.z, v.w));
  }
  __syncthreads();  // [barrier 1] z staged

  const int nt = w & 3, mset = (w >> 2) * 3;
  const int vsel = nt & 1, hsel = nt >> 1;
  const float qsc = vsel ? 1.0f : QU_SCALE;
  const float* wmat = vsel ? wv : wu;

  float aacc[4][6] = {};
  const f32x4 zf = {0.f, 0.f, 0.f, 0.f};

  // ---- preload W[0] fragments ----
  u32x4 wbh[4];
  {
    const float* wrow = wmat + ((size_t)b * ND + hsel * NR + lm) * ND;
#pragma unroll
    for (int ks = 0; ks < 4; ++ks) {
      float4 x0 = *(const float4*)(wrow + ks * 32 + lk * 8);
      float4 x1 = *(const float4*)(wrow + ks * 32 + lk * 8 + 4);
      wbh[ks] = u32x4{hi2(x0.x, x0.y), hi2(x0.z, x0.w),
                      hi2(x1.x, x1.y), hi2(x1.z, x1.w)};
    }
  }

  // ---- proj sweep: all 4 head-pairs, no barriers (disjoint qall cells) ----
#pragma unroll
  for (int hp = 0; hp < 4; ++hp) {
    float4 pf[8];
    const bool havepf = hp < 3;
    if (havepf) {
      const int hdn = 2 * (hp + 1) + hsel;
      const float* wrow = wmat + ((size_t)b * ND + hdn * NR + lm) * ND;
#pragma unroll
      for (int ks = 0; ks < 4; ++ks) {
        pf[2 * ks + 0] = *(const float4*)(wrow + ks * 32 + lk * 8);
        pf[2 * ks + 1] = *(const float4*)(wrow + ks * 32 + lk * 8 + 4);
      }
    }
    f32x4 pacc[3] = {zf, zf, zf};
#pragma unroll
    for (int ks = 0; ks < 4; ++ks) {
#pragma unroll
      for (int mm = 0; mm < 3; ++mm) {
        int row = (mset + mm) * 16 + lm;
        short8 ah = *(const short8*)&zhi[row * TS_Z + ks * 32 + lk * 8];
        pacc[mm] = MFMA(ah, s8(wbh[ks]), pacc[mm]);
      }
    }
#pragma unroll
    for (int mm = 0; mm < 3; ++mm) {
#pragma unroll
      for (int r = 0; r < 4; ++r) {
        float v = pacc[mm][r] * qsc;
        int row = (mset + mm) * 16 + lk * 4 + r;
        qall[row * TS_QA + hp * 64 + nt * 16 + lm] = bfh(v);
      }
    }
    if (havepf) {
#pragma unroll
      for (int ks = 0; ks < 4; ++ks) {
        float4 x0 = pf[2 * ks + 0], x1 = pf[2 * ks + 1];
        wbh[ks] = u32x4{hi2(x0.x, x0.y), hi2(x0.z, x0.w),
                        hi2(x1.x, x1.y), hi2(x1.z, x1.w)};
      }
    }
  }
  __syncthreads();  // [barrier 2] all Q written; zhi now dead

  // ---- logits sweep: all 4 hp (K=16 exact) + softmax; waves 0-5 ----
  if (w < 6) {
#pragma unroll
    for (int hp = 0; hp < 4; ++hp) {
#pragma unroll
      for (int hh = 0; hh < 2; ++hh) {
        s16x4 ah = *(const s16x4*)&qall[(w * 16 + lm) * TS_QA + hp * 64 + 32 * hh + lk * 4];
        f32x4 s[6];
#pragma unroll
        for (int qt = 0; qt < 6; ++qt) {
          s16x4 bh = *(const s16x4*)&qall[(qt * 16 + lm) * TS_QA + hp * 64 + 32 * hh + 16 + lk * 4];
          s[qt] = MFMA16(ah, bh, zf);
        }
#pragma unroll
        for (int r = 0; r < 4; ++r) {
          float e[6], sum = 0.f;
#pragma unroll
          for (int qt = 0; qt < 6; ++qt) { e[qt] = fexp2(s[qt][r]); sum += e[qt]; }
          sum += __shfl_xor(sum, 1);
          sum += __shfl_xor(sum, 2);
          sum += __shfl_xor(sum, 4);
          sum += __shfl_xor(sum, 8);
          float inv = __builtin_amdgcn_rcpf(sum);
#pragma unroll
          for (int qt = 0; qt < 6; ++qt) aacc[r][qt] += e[qt] * inv;
        }
      }
    }
  }

  // ---- PV B-fragments: gather z^T from global (L2-hot) ----
  u32x4 zb[3];
#pragma unroll
  for (int ks = 0; ks < 3; ++ks) {
    const float* gq = zg + (size_t)(ks * 32 + lk * 8) * ND + w * 16 + lm;
    float g0 = gq[0 * ND], g1 = gq[1 * ND], g2 = gq[2 * ND], g3 = gq[3 * ND];
    float g4 = gq[4 * ND], g5 = gq[5 * ND], g6 = gq[6 * ND], g7 = gq[7 * ND];
    zb[ks] = u32x4{hi2(g0, g1), hi2(g2, g3), hi2(g4, g5), hi2(g6, g7)};
  }
  // ---- abar-hi into LDS (over dead zhi) ----
  if (w < 6) {
#pragma unroll
    for (int r = 0; r < 4; ++r)
#pragma unroll
      for (int qt = 0; qt < 6; ++qt)
        ahi[(w * 16 + lk * 4 + r) * TS_T + qt * 16 + lm] = bfh(aacc[r][qt] * 0.125f);
  }
  __syncthreads();  // [barrier 3] abar ready

  // ---- PV: m_t = abar @ z (hi-only both sides) ----
  float* og = out + ((size_t)(b * NC + c) * NP) * ND;
  f32x4 oacc[6] = {zf, zf, zf, zf, zf, zf};
#pragma unroll
  for (int ks = 0; ks < 3; ++ks) {
    short8 bh = s8(zb[ks]);
#pragma unroll
    for (int m = 0; m < 6; ++m) {
      short8 a = *(const short8*)&ahi[(m * 16 + lm) * TS_T + ks * 32 + lk * 8];
      oacc[m] = MFMA(a, bh, oacc[m]);
    }
  }
#pragma unroll
  for (int m = 0; m < 6; ++m)
#pragma unroll
    for (int r = 0; r < 4; ++r)
      og[(m * 16 + lk * 4 + r) * ND + w * 16 + lm] = oacc[m][r];
}

// ================= channel-message body: idx -> (b, p) =================
// (R25 structure, unchanged: Q and W double-buffered, ONE barrier per hp;
//  K=16 logits, TS_Q=76)
__device__ __forceinline__ void cmsg_body(
    int idx, const float* __restrict__ qz, const float* __restrict__ wu,
    const float* __restrict__ wv, float* __restrict__ out, short* smem) {
  short* qA   = smem;                        // [128][76]
  short* qB   = smem + NC * TS_Q;
  short* wstA = smem + 2 * NC * TS_Q;        // [4][16][136]
  short* wstB = wstA + 4 * 16 * TS_W;

  const int tid = threadIdx.x;
  const int l = tid & 63, w = tid >> 6;
  const int lm = l & 15, lk = l >> 4;
  const int p = idx % 96, b = idx / 96;

  // chunk decode for cooperative W staging: ci in [0,1024)
  const int ci0 = tid, ci1 = tid + 512;
  const int nt0 = ci0 >> 8, row0 = (ci0 >> 4) & 15, colc0 = ci0 & 15;
  const int nt1 = ci1 >> 8, row1 = (ci1 >> 4) & 15, colc1 = ci1 & 15;
  const int vs0 = nt0 & 1, vs1 = nt1 & 1;

  // ---- stage W[0] directly into wstA ----
#pragma unroll
  for (int cc = 0; cc < 2; ++cc) {
    int nt = cc ? nt1 : nt0, row = cc ? row1 : row0, colc = cc ? colc1 : colc0;
    int vs = nt & 1, hd = (nt >> 1);
    const float* src = (vs ? wv : wu) + ((size_t)b * ND + hd * NR + row) * ND + colc * 8;
    float4 x0 = *(const float4*)src, x1 = *(const float4*)(src + 4);
    *(u32x4*)&wstA[nt * (16 * TS_W) + row * TS_W + colc * 8] =
        u32x4{hi2(x0.x, x0.y), hi2(x0.z, x0.w), hi2(x1.x, x1.y), hi2(x1.z, x1.w)};
  }

  // ---- z-hi A-fragments for this wave's m-tile ----
  u32x4 zah[4];
  {
    const float* zrow = qz + ((size_t)(b * NC + w * 16 + lm) * NP + p) * ND;
#pragma unroll
    for (int ks = 0; ks < 4; ++ks) {
      float4 x0 = *(const float4*)(zrow + ks * 32 + lk * 8);
      float4 x1 = *(const float4*)(zrow + ks * 32 + lk * 8 + 4);
      zah[ks] = u32x4{hi2(x0.x, x0.y), hi2(x0.z, x0.w),
                      hi2(x1.x, x1.y), hi2(x1.z, x1.w)};
    }
  }
  __syncthreads();  // W[0] ready

  float aacc[4][8] = {};
  const f32x4 zf = {0.f, 0.f, 0.f, 0.f};

  short* qcur = qA;
  short* qnxt = qB;
  short* wcur = wstA;
  short* wnxt = wstB;
  for (int hp = 0; hp < 4; ++hp) {
    // ---- issue W[hp+1] prefetch loads (latency hides under proj) ----
    float4 f00 = {}, f01 = {}, f10 = {}, f11 = {};
    const bool havepf = hp < 3;
    if (havepf) {
      const int hd0 = 2 * (hp + 1) + (nt0 >> 1), hd1 = 2 * (hp + 1) + (nt1 >> 1);
      const float* s0 = (vs0 ? wv : wu) + ((size_t)b * ND + hd0 * NR + row0) * ND + colc0 * 8;
      const float* s1 = (vs1 ? wv : wu) + ((size_t)b * ND + hd1 * NR + row1) * ND + colc1 * 8;
      f00 = *(const float4*)s0; f01 = *(const float4*)(s0 + 4);
      f10 = *(const float4*)s1; f11 = *(const float4*)(s1 + 4);
    }

    // ---- projection: pure bf16, z-hi × W-hi from wcur; writes qcur ----
#pragma unroll
    for (int nt = 0; nt < 4; ++nt) {
      f32x4 pacc = zf;
#pragma unroll
      for (int ks = 0; ks < 4; ++ks) {
        short8 bh = *(const short8*)&wcur[nt * (16 * TS_W) + lm * TS_W + ks * 32 + lk * 8];
        pacc = MFMA(s8(zah[ks]), bh, pacc);
      }
      const float qsc = (nt & 1) ? 1.0f : QU_SCALE;
#pragma unroll
      for (int r = 0; r < 4; ++r) {
        float v = pacc[r] * qsc;
        qcur[(w * 16 + lk * 4 + r) * TS_Q + nt * 16 + lm] = bfh(v);
      }
    }
    // ---- commit prefetched W[hp+1] into wnxt ----
    if (havepf) {
      *(u32x4*)&wnxt[nt0 * (16 * TS_W) + row0 * TS_W + colc0 * 8] =
          u32x4{hi2(f00.x, f00.y), hi2(f00.z, f00.w), hi2(f01.x, f01.y), hi2(f01.z, f01.w)};
      *(u32x4*)&wnxt[nt1 * (16 * TS_W) + row1 * TS_W + colc1 * 8] =
          u32x4{hi2(f10.x, f10.y), hi2(f10.z, f10.w), hi2(f11.x, f11.y), hi2(f11.z, f11.w)};
    }
    __syncthreads();  // qcur ready + wnxt committed + all wcur reads done

    // ---- logits (K=16 exact, all lanes) + softmax over d' ----
#pragma unroll
    for (int hh = 0; hh < 2; ++hh) {
      s16x4 ah = *(const s16x4*)&qcur[(w * 16 + lm) * TS_Q + 32 * hh + lk * 4];
      f32x4 s[8];
#pragma unroll
      for (int qt = 0; qt < 8; ++qt) {
        s16x4 bh = *(const s16x4*)&qcur[(qt * 16 + lm) * TS_Q + 32 * hh + 16 + lk * 4];
        s[qt] = MFMA16(ah, bh, zf);
      }
#pragma unroll
      for (int r = 0; r < 4; ++r) {
        float e[8], sum = 0.f;
#pragma unroll
        for (int qt = 0; qt < 8; ++qt) { e[qt] = fexp2(s[qt][r]); sum += e[qt]; }
        sum += __shfl_xor(sum, 1);
        sum += __shfl_xor(sum, 2);
        sum += __shfl_xor(sum, 4);
        sum += __shfl_xor(sum, 8);
        float inv = __builtin_amdgcn_rcpf(sum);
#pragma unroll
        for (int qt = 0; qt < 8; ++qt) aacc[r][qt] += e[qt] * inv;
      }
    }
    // no barrier: next proj writes q-other & reads w-other (both fenced above)
    short* tq = qcur; qcur = qnxt; qnxt = tq;
    short* tw = wcur; wcur = wnxt; wnxt = tw;
  }

  // ---- elementwise finish: m_c = (abar/8) * z, exact fp32 z from global ----
#pragma unroll
  for (int r = 0; r < 4; ++r) {
    int cc = w * 16 + lk * 4 + r;
    const float* zrow = qz + ((size_t)(b * NC + cc) * NP + p) * ND;
    float* orow = out + ((size_t)(b * NC + cc) * NP + p) * ND;
#pragma unroll
    for (int qt = 0; qt < 8; ++qt) {
      int d = qt * 16 + lm;
      orow[d] = 0.125f * aacc[r][qt] * zrow[d];
    }
  }
}

// ================= fused dispatcher =================
// (512,2), LDS 77,568 B (tmsg all-heads), 2 blocks/CU (2x77,568 = 155,136
// <= 163,840; VGPR quantum keeps residency at 2 regardless).
__global__ __launch_bounds__(512, 2)
void fused_kernel(const float* __restrict__ qz, const float* __restrict__ tuw,
                  const float* __restrict__ tvw, const float* __restrict__ cuw,
                  const float* __restrict__ cvw, float* __restrict__ out_t,
                  float* __restrict__ out_c) {
  __shared__ __align__(16) short smem[38784];  // 77,568 B
  const int bid = blockIdx.x;
  const int r7 = bid % 7, q7 = bid / 7;
  if (r7 < 4)
    tmsg_body(q7 * 4 + r7, qz, tuw, tvw, out_t, smem);
  else
    cmsg_body(q7 * 3 + (r7 - 4), qz, cuw, cvw, out_c, smem);
}

extern "C" void kernel_launch(void* const* d_in, const int* in_sizes, int n_in,
                              void* d_out, int out_size, void* d_ws, size_t ws_size,
                              hipStream_t stream) {
  const float* qz  = (const float*)d_in[0];
  const float* tuw = (const float*)d_in[1];
  const float* tvw = (const float*)d_in[2];
  const float* cuw = (const float*)d_in[3];
  const float* cvw = (const float*)d_in[4];
  float* out_t = (float*)d_out;
  float* out_c = out_t + (size_t)NB * NC * NP * ND;

  fused_kernel<<<1792, 512, 0, stream>>>(qz, tuw, tvw, cuw, cvw, out_t, out_c);
}

// Round 27
// 103.924 us; speedup vs baseline: 1.1013x; 1.1013x over previous
//
#include <hip/hip_runtime.h>
#include <math.h>

#define NB 8
#define NC 128
#define NP 96
#define ND 128
#define NH 8
#define NR 16

typedef __attribute__((ext_vector_type(8))) short short8;
typedef __attribute__((ext_vector_type(4))) short s16x4;
typedef __attribute__((ext_vector_type(4))) float f32x4;
typedef __attribute__((ext_vector_type(4))) unsigned u32x4;

#define MFMA(a, b, c) __builtin_amdgcn_mfma_f32_16x16x32_bf16((a), (b), (c), 0, 0, 0)

// K=16 bf16 MFMA for logits (exact K, all 64 lanes, A/B = 2 VGPRs)
#if __has_builtin(__builtin_amdgcn_mfma_f32_16x16x16_bf16)
#define MFMA16(a, b, c) __builtin_amdgcn_mfma_f32_16x16x16_bf16((a), (b), (c), 0, 0, 0)
#else
#define MFMA16(a, b, c) __builtin_amdgcn_mfma_f32_16x16x16bf16_1k((a), (b), (c), 0, 0, 0)
#endif

// log2(e) folded into the Qu projection scale so softmax uses exp2 directly
#define QU_SCALE (0.25f * 1.44269504f)

__device__ __forceinline__ short8 s8(u32x4 u) { return __builtin_bit_cast(short8, u); }

// fp32 -> bf16 via native cast (RNE; compiler emits cvt_pk for pairs)
__device__ __forceinline__ short bfh(float x) {
  __bf16 b = (__bf16)x;
  return __builtin_bit_cast(short, b);
}

// hi pack of 2 floats -> 2 bf16 in one u32
__device__ __forceinline__ unsigned hi2(float a, float b) {
  unsigned short ua = __builtin_bit_cast(unsigned short, (__bf16)a);
  unsigned short ub = __builtin_bit_cast(unsigned short, (__bf16)b);
  return (unsigned)ua | ((unsigned)ub << 16);
}

// fast exp2: raw v_exp_f32
__device__ __forceinline__ float fexp2(float x) {
#if __has_builtin(__builtin_amdgcn_exp2f)
  return __builtin_amdgcn_exp2f(x);
#else
  return exp2f(x);
#endif
}

// LDS row strides in shorts
#define TS_Z 136   // z-hi   [96][136]
#define TS_Q 76    // Q-hi   [rows][76]  (38 words: ~2-way on b64 logits reads)
#define TS_T 104   // abar   [96][104]
#define TS_W 136   // W tile [16][136] per nt

// ================= time-message body: idx -> (b, c) =================
// (R21 structure: single barrier per hp, W software pipeline, PV gather;
//  K=16 logits MFMA)
__device__ __forceinline__ void tmsg_body(
    int idx, const float* __restrict__ qz, const float* __restrict__ wu,
    const float* __restrict__ wv, float* __restrict__ out, short* smem) {
  short* zhi = smem;                    // [96][136]
  short* qA  = smem + NP * TS_Z;        // [96][76]
  short* qB  = qA + NP * TS_Q;
  short* ahi = smem;                    // [96][104] (phase2, over dead zhi)

  const int tid = threadIdx.x;
  const int l = tid & 63, w = tid >> 6;
  const int lm = l & 15, lk = l >> 4;
  const int c = idx & 127, b = idx >> 7;
  const float* zg = qz + ((size_t)(b * NC + c) * NP) * ND;

  // ---- stage z -> bf16 hi only ----
  for (int i = tid; i < NP * 32; i += 512) {
    int p = i >> 5, s = i & 31;
    float4 v = ((const float4*)zg)[i];
    *(uint2*)&zhi[p * TS_Z + 4 * s] = make_uint2(hi2(v.x, v.y), hi2(v.z, v.w));
  }
  __syncthreads();

  const int nt = w & 3, mset = (w >> 2) * 3;
  const int vsel = nt & 1, hsel = nt >> 1;
  const float qsc = vsel ? 1.0f : QU_SCALE;
  const float* wmat = vsel ? wv : wu;

  float aacc[4][6] = {};
  const f32x4 zf = {0.f, 0.f, 0.f, 0.f};

  // ---- preload W[0] fragments ----
  u32x4 wbh[4];
  {
    const float* wrow = wmat + ((size_t)b * ND + hsel * NR + lm) * ND;
#pragma unroll
    for (int ks = 0; ks < 4; ++ks) {
      float4 x0 = *(const float4*)(wrow + ks * 32 + lk * 8);
      float4 x1 = *(const float4*)(wrow + ks * 32 + lk * 8 + 4);
      wbh[ks] = u32x4{hi2(x0.x, x0.y), hi2(x0.z, x0.w),
                      hi2(x1.x, x1.y), hi2(x1.z, x1.w)};
    }
  }

  short* qcur = qA;
  short* qnxt = qB;
  for (int hp = 0; hp < 4; ++hp) {
    // ---- issue W[hp+1] raw loads (convert at loop bottom) ----
    float4 pf[8];
    const bool havepf = hp < 3;
    if (havepf) {
      const int hdn = 2 * (hp + 1) + hsel;
      const float* wrow = wmat + ((size_t)b * ND + hdn * NR + lm) * ND;
#pragma unroll
      for (int ks = 0; ks < 4; ++ks) {
        pf[2 * ks + 0] = *(const float4*)(wrow + ks * 32 + lk * 8);
        pf[2 * ks + 1] = *(const float4*)(wrow + ks * 32 + lk * 8 + 4);
      }
    }

    // ---- projection: pure bf16, z-hi × W-hi; writes Q[parity] ----
    f32x4 pacc[3] = {zf, zf, zf};
#pragma unroll
    for (int ks = 0; ks < 4; ++ks) {
#pragma unroll
      for (int mm = 0; mm < 3; ++mm) {
        int row = (mset + mm) * 16 + lm;
        short8 ah = *(const short8*)&zhi[row * TS_Z + ks * 32 + lk * 8];
        pacc[mm] = MFMA(ah, s8(wbh[ks]), pacc[mm]);
      }
    }
#pragma unroll
    for (int mm = 0; mm < 3; ++mm) {
#pragma unroll
      for (int r = 0; r < 4; ++r) {
        float v = pacc[mm][r] * qsc;
        int row = (mset + mm) * 16 + lk * 4 + r, col = nt * 16 + lm;
        qcur[row * TS_Q + col] = bfh(v);
      }
    }
    __syncthreads();  // Q[parity] ready

    // ---- logits (K=16 exact, all lanes) + softmax; waves 0-5 ----
    if (w < 6) {
#pragma unroll
      for (int hh = 0; hh < 2; ++hh) {
        s16x4 ah = *(const s16x4*)&qcur[(w * 16 + lm) * TS_Q + 32 * hh + lk * 4];
        f32x4 s[6];
#pragma unroll
        for (int qt = 0; qt < 6; ++qt) {
          s16x4 bh = *(const s16x4*)&qcur[(qt * 16 + lm) * TS_Q + 32 * hh + 16 + lk * 4];
          s[qt] = MFMA16(ah, bh, zf);
        }
#pragma unroll
        for (int r = 0; r < 4; ++r) {
          float e[6], sum = 0.f;
#pragma unroll
          for (int qt = 0; qt < 6; ++qt) { e[qt] = fexp2(s[qt][r]); sum += e[qt]; }
          sum += __shfl_xor(sum, 1);
          sum += __shfl_xor(sum, 2);
          sum += __shfl_xor(sum, 4);
          sum += __shfl_xor(sum, 8);
          float inv = __builtin_amdgcn_rcpf(sum);
#pragma unroll
          for (int qt = 0; qt < 6; ++qt) aacc[r][qt] += e[qt] * inv;
        }
      }
    }
    // ---- convert prefetched W[hp+1] -> wbh ----
    if (havepf) {
#pragma unroll
      for (int ks = 0; ks < 4; ++ks) {
        float4 x0 = pf[2 * ks + 0], x1 = pf[2 * ks + 1];
        wbh[ks] = u32x4{hi2(x0.x, x0.y), hi2(x0.z, x0.w),
                        hi2(x1.x, x1.y), hi2(x1.z, x1.w)};
      }
    }
    short* t = qcur; qcur = qnxt; qnxt = t;  // buffers disjoint: no barrier
  }
  __syncthreads();  // all logits done; zhi and Q now dead

  // ---- PV B-fragments: gather z^T from global (L2-hot) ----
  u32x4 zb[3];
#pragma unroll
  for (int ks = 0; ks < 3; ++ks) {
    const float* gq = zg + (size_t)(ks * 32 + lk * 8) * ND + w * 16 + lm;
    float g0 = gq[0 * ND], g1 = gq[1 * ND], g2 = gq[2 * ND], g3 = gq[3 * ND];
    float g4 = gq[4 * ND], g5 = gq[5 * ND], g6 = gq[6 * ND], g7 = gq[7 * ND];
    zb[ks] = u32x4{hi2(g0, g1), hi2(g2, g3), hi2(g4, g5), hi2(g6, g7)};
  }
  // ---- abar-hi into LDS (over dead zhi) ----
  if (w < 6) {
#pragma unroll
    for (int r = 0; r < 4; ++r)
#pragma unroll
      for (int qt = 0; qt < 6; ++qt)
        ahi[(w * 16 + lk * 4 + r) * TS_T + qt * 16 + lm] = bfh(aacc[r][qt] * 0.125f);
  }
  __syncthreads();

  // ---- PV: m_t = abar @ z (hi-only both sides) ----
  float* og = out + ((size_t)(b * NC + c) * NP) * ND;
  f32x4 oacc[6] = {zf, zf, zf, zf, zf, zf};
#pragma unroll
  for (int ks = 0; ks < 3; ++ks) {
    short8 bh = s8(zb[ks]);
#pragma unroll
    for (int m = 0; m < 6; ++m) {
      short8 a = *(const short8*)&ahi[(m * 16 + lm) * TS_T + ks * 32 + lk * 8];
      oacc[m] = MFMA(a, bh, oacc[m]);
    }
  }
#pragma unroll
  for (int m = 0; m < 6; ++m)
#pragma unroll
    for (int r = 0; r < 4; ++r)
      og[(m * 16 + lk * 4 + r) * ND + w * 16 + lm] = oacc[m][r];
}

// ================= channel-message body: idx -> (b, p) =================
// (R22 structure: Q and W double-buffered, ONE barrier per hp; K=16 logits)
__device__ __forceinline__ void cmsg_body(
    int idx, const float* __restrict__ qz, const float* __restrict__ wu,
    const float* __restrict__ wv, float* __restrict__ out, short* smem) {
  short* qA   = smem;                        // [128][76]
  short* qB   = smem + NC * TS_Q;
  short* wstA = smem + 2 * NC * TS_Q;        // [4][16][136]
  short* wstB = wstA + 4 * 16 * TS_W;

  const int tid = threadIdx.x;
  const int l = tid & 63, w = tid >> 6;
  const int lm = l & 15, lk = l >> 4;
  const int p = idx % 96, b = idx / 96;

  // chunk decode for cooperative W staging: ci in [0,1024)
  const int ci0 = tid, ci1 = tid + 512;
  const int nt0 = ci0 >> 8, row0 = (ci0 >> 4) & 15, colc0 = ci0 & 15;
  const int nt1 = ci1 >> 8, row1 = (ci1 >> 4) & 15, colc1 = ci1 & 15;
  const int vs0 = nt0 & 1, vs1 = nt1 & 1;

  // ---- stage W[0] directly into wstA ----
#pragma unroll
  for (int cc = 0; cc < 2; ++cc) {
    int nt = cc ? nt1 : nt0, row = cc ? row1 : row0, colc = cc ? colc1 : colc0;
    int vs = nt & 1, hd = (nt >> 1);
    const float* src = (vs ? wv : wu) + ((size_t)b * ND + hd * NR + row) * ND + colc * 8;
    float4 x0 = *(const float4*)src, x1 = *(const float4*)(src + 4);
    *(u32x4*)&wstA[nt * (16 * TS_W) + row * TS_W + colc * 8] =
        u32x4{hi2(x0.x, x0.y), hi2(x0.z, x0.w), hi2(x1.x, x1.y), hi2(x1.z, x1.w)};
  }

  // ---- z-hi A-fragments for this wave's m-tile ----
  u32x4 zah[4];
  {
    const float* zrow = qz + ((size_t)(b * NC + w * 16 + lm) * NP + p) * ND;
#pragma unroll
    for (int ks = 0; ks < 4; ++ks) {
      float4 x0 = *(const float4*)(zrow + ks * 32 + lk * 8);
      float4 x1 = *(const float4*)(zrow + ks * 32 + lk * 8 + 4);
      zah[ks] = u32x4{hi2(x0.x, x0.y), hi2(x0.z, x0.w),
                      hi2(x1.x, x1.y), hi2(x1.z, x1.w)};
    }
  }
  __syncthreads();  // W[0] ready

  float aacc[4][8] = {};
  const f32x4 zf = {0.f, 0.f, 0.f, 0.f};

  short* qcur = qA;
  short* qnxt = qB;
  short* wcur = wstA;
  short* wnxt = wstB;
  for (int hp = 0; hp < 4; ++hp) {
    // ---- issue W[hp+1] prefetch loads (latency hides under proj) ----
    float4 f00 = {}, f01 = {}, f10 = {}, f11 = {};
    const bool havepf = hp < 3;
    if (havepf) {
      const int hd0 = 2 * (hp + 1) + (nt0 >> 1), hd1 = 2 * (hp + 1) + (nt1 >> 1);
      const float* s0 = (vs0 ? wv : wu) + ((size_t)b * ND + hd0 * NR + row0) * ND + colc0 * 8;
      const float* s1 = (vs1 ? wv : wu) + ((size_t)b * ND + hd1 * NR + row1) * ND + colc1 * 8;
      f00 = *(const float4*)s0; f01 = *(const float4*)(s0 + 4);
      f10 = *(const float4*)s1; f11 = *(const float4*)(s1 + 4);
    }

    // ---- projection: pure bf16, z-hi × W-hi from wcur; writes qcur ----
#pragma unroll
    for (int nt = 0; nt < 4; ++nt) {
      f32x4 pacc = zf;
#pragma unroll
      for (int ks = 0; ks < 4; ++ks) {
        short8 bh = *(const short8*)&wcur[nt * (16 * TS_W) + lm * TS_W + ks * 32 + lk * 8];
        pacc = MFMA(s8(zah[ks]), bh, pacc);
      }
      const float qsc = (nt & 1) ? 1.0f : QU_SCALE;
#pragma unroll
      for (int r = 0; r < 4; ++r) {
        float v = pacc[r] * qsc;
        qcur[(w * 16 + lk * 4 + r) * TS_Q + nt * 16 + lm] = bfh(v);
      }
    }
    // ---- commit prefetched W[hp+1] into wnxt ----
    if (havepf) {
      *(u32x4*)&wnxt[nt0 * (16 * TS_W) + row0 * TS_W + colc0 * 8] =
          u32x4{hi2(f00.x, f00.y), hi2(f00.z, f00.w), hi2(f01.x, f01.y), hi2(f01.z, f01.w)};
      *(u32x4*)&wnxt[nt1 * (16 * TS_W) + row1 * TS_W + colc1 * 8] =
          u32x4{hi2(f10.x, f10.y), hi2(f10.z, f10.w), hi2(f11.x, f11.y), hi2(f11.z, f11.w)};
    }
    __syncthreads();  // qcur ready + wnxt committed + all wcur reads done

    // ---- logits (K=16 exact, all lanes) + softmax over d' ----
#pragma unroll
    for (int hh = 0; hh < 2; ++hh) {
      s16x4 ah = *(const s16x4*)&qcur[(w * 16 + lm) * TS_Q + 32 * hh + lk * 4];
      f32x4 s[8];
#pragma unroll
      for (int qt = 0; qt < 8; ++qt) {
        s16x4 bh = *(const s16x4*)&qcur[(qt * 16 + lm) * TS_Q + 32 * hh + 16 + lk * 4];
        s[qt] = MFMA16(ah, bh, zf);
      }
#pragma unroll
      for (int r = 0; r < 4; ++r) {
        float e[8], sum = 0.f;
#pragma unroll
        for (int qt = 0; qt < 8; ++qt) { e[qt] = fexp2(s[qt][r]); sum += e[qt]; }
        sum += __shfl_xor(sum, 1);
        sum += __shfl_xor(sum, 2);
        sum += __shfl_xor(sum, 4);
        sum += __shfl_xor(sum, 8);
        float inv = __builtin_amdgcn_rcpf(sum);
#pragma unroll
        for (int qt = 0; qt < 8; ++qt) aacc[r][qt] += e[qt] * inv;
      }
    }
    // no barrier: next proj writes q-other & reads w-other (both fenced above)
    short* tq = qcur; qcur = qnxt; qnxt = tq;
    short* tw = wcur; wcur = wnxt; wnxt = tw;
  }

  // ---- elementwise finish: m_c = (abar/8) * z, exact fp32 z from global ----
#pragma unroll
  for (int r = 0; r < 4; ++r) {
    int cc = w * 16 + lk * 4 + r;
    const float* zrow = qz + ((size_t)(b * NC + cc) * NP + p) * ND;
    float* orow = out + ((size_t)(b * NC + cc) * NP + p) * ND;
#pragma unroll
    for (int qt = 0; qt < 8; ++qt) {
      int d = qt * 16 + lm;
      orow[d] = 0.125f * aacc[r][qt] * zrow[d];
    }
  }
}

// ================= fused dispatcher =================
// (512,2), LDS 73,728 B, 2 blocks/CU (R22-verified VGPR quantum; 2x73,728
// = 147,456 <= 160 KB).
__global__ __launch_bounds__(512, 2)
void fused_kernel(const float* __restrict__ qz, const float* __restrict__ tuw,
                  const float* __restrict__ tvw, const float* __restrict__ cuw,
                  const float* __restrict__ cvw, float* __restrict__ out_t,
                  float* __restrict__ out_c) {
  __shared__ __align__(16) short smem[36864];  // 73,728 B
  const int bid = blockIdx.x;
  const int r7 = bid % 7, q7 = bid / 7;
  if (r7 < 4)
    tmsg_body(q7 * 4 + r7, qz, tuw, tvw, out_t, smem);
  else
    cmsg_body(q7 * 3 + (r7 - 4), qz, cuw, cvw, out_c, smem);
}

extern "C" void kernel_launch(void* const* d_in, const int* in_sizes, int n_in,
                              void* d_out, int out_size, void* d_ws, size_t ws_size,
                              hipStream_t stream) {
  const float* qz  = (const float*)d_in[0];
  const float* tuw = (const float*)d_in[1];
  const float* tvw = (const float*)d_in[2];
  const float* cuw = (const float*)d_in[3];
  const float* cvw = (const float*)d_in[4];
  float* out_t = (float*)d_out;
  float* out_c = out_t + (size_t)NB * NC * NP * ND;

  fused_kernel<<<1792, 512, 0, stream>>>(qz, tuw, tvw, cuw, cvw, out_t, out_c);
}